// Round 17
// baseline (132.147 us; speedup 1.0000x reference)
//
#include <hip/hip_runtime.h>
#include <hip/hip_bf16.h>

// CalcSpixelFeats R17. Base = R14 (109.9us best). R16 (pixel-ordered recs +
// permutation) regressed: +33% record volume + dependent pi chain.
// R17 keeps R14's skeleton, two changes:
//  1) split record planes: recF [bucket][cap][64B] line-aligned (full-line
//     scattered stores, no RMW; R10 measured 38MB vs 25 ideal for 96B-stride)
//     + recW [bucket][cap][32B] w-plane.
//  2) finalize folded into scan via per-target done counters (split-K
//     semaphore; cross-XCD visibility of fsum atomics validated by R15's
//     passing run). Saves one dispatch.

#define CCH  32         // channels, fixed by problem
#define TPB  1024       // prep block threads (1 px/thread)
#define STPB 512        // scan block: 16 ch-pair lanes x 32 record groups
#define CAPC 384        // bucket capacity (mean 256, sd 16 -> +8 sigma)
#define CNTS 16         // counter stride in dwords (64 B line)
#define KMAX 256

__device__ __forceinline__ unsigned pack_bf16(float a, float b) {
    unsigned ua = __float_as_uint(a);
    unsigned ub = __float_as_uint(b);
    ua = (ua + 0x7FFFu + ((ua >> 16) & 1u)) >> 16;   // RNE
    ub = (ub + 0x7FFFu + ((ub >> 16) & 1u)) >> 16;
    return ua | (ub << 16);
}
__device__ __forceinline__ float bf_lo(unsigned u) {
    return __uint_as_float(u << 16);
}
__device__ __forceinline__ float bf_hi(unsigned u) {
    return __uint_as_float(u & 0xFFFF0000u);
}

__global__ __launch_bounds__(TPB, 4) void spx_prep_kernel(
    const float* __restrict__ pf,      // [B][C][P]
    const float* __restrict__ assoc,   // [B][9][P]
    const int*   __restrict__ idxmap,  // [B][P]
    const int*   __restrict__ nw_p,
    const int*   __restrict__ nh_p,
    int*         __restrict__ cnt,     // [B*K][CNTS] (padded counters)
    unsigned*    __restrict__ recF,    // [B*K][cap][16] feat plane (64B)
    unsigned*    __restrict__ recW,    // [B*K][cap][8]  w plane (32B)
    float*       __restrict__ fsum,    // [B*K][CCH+1] target accumulator
    int P, int K, int cap, int bpb)    // bpb = P / TPB
{
    __shared__ int hist[KMAX];
    __shared__ int bases[KMAX];

    const int b   = blockIdx.x / bpb;
    const int blk = blockIdx.x - b * bpb;
    const int tid = threadIdx.x;
    const int p   = blk * TPB + tid;   // within batch (1 px/thread)

    if (tid < KMAX) hist[tid] = 0;
    __syncthreads();

    const int*   ix_b = idxmap + (size_t)b * P;
    const float* pf_b = pf     + (size_t)b * CCH * P;
    const float* as_b = assoc  + (size_t)b * 9 * P;

    const int idx  = ix_b[p];
    const int rank = atomicAdd(&hist[idx], 1);   // native LDS int atomic

    // bulk loads: all issue before the reservation barrier
    unsigned u[16];
#pragma unroll
    for (int c2 = 0; c2 < 16; ++c2) {
        const float f0 = pf_b[(size_t)(2*c2  ) * P + p];
        const float f1 = pf_b[(size_t)(2*c2+1) * P + p];
        u[c2] = pack_bf16(f0, f1);
    }
    float wv[9];
#pragma unroll
    for (int j = 0; j < 9; ++j) wv[j] = as_b[(size_t)j * P + p];

    __syncthreads();
    if (tid < KMAX)
        bases[tid] = atomicAdd(&cnt[(b * K + tid) * CNTS], hist[tid]);
    __syncthreads();

    const int pos = bases[idx] + rank;

    if (pos < cap) {
        const size_t slot = (size_t)(b * K + idx) * cap + pos;
        uint4* f4 = (uint4*)(recF + slot * 16);       // 64B, line-aligned
        f4[0] = make_uint4(u[0],  u[1],  u[2],  u[3]);
        f4[1] = make_uint4(u[4],  u[5],  u[6],  u[7]);
        f4[2] = make_uint4(u[8],  u[9],  u[10], u[11]);
        f4[3] = make_uint4(u[12], u[13], u[14], u[15]);
        uint4* w4 = (uint4*)(recW + slot * 8);        // 32B-aligned
        w4[0] = make_uint4(pack_bf16(wv[0], wv[1]), pack_bf16(wv[2], wv[3]),
                           pack_bf16(wv[4], wv[5]), pack_bf16(wv[6], wv[7]));
        w4[1] = make_uint4(pack_bf16(wv[8], 0.0f), 0u, 0u, 0u);
    } else {
        // rare overflow: accumulate into fsum directly (native fp atomics)
        const int nw = nw_p[0], nh = nh_p[0];
        const int iy = idx / nw, ixx = idx - (idx / nw) * nw;
#pragma unroll
        for (int j = 0; j < 9; ++j) {
            const int ty = iy + j / 3 - 1, tx = ixx + j % 3 - 1;
            if (tx >= 0 && tx < nw && ty >= 0 && ty < nh) {
                float* o = fsum + (size_t)(b * K + ty * nw + tx) * (CCH + 1);
#pragma unroll
                for (int c2 = 0; c2 < 16; ++c2) {
                    unsafeAtomicAdd(&o[2*c2],     wv[j] * bf_lo(u[c2]));
                    unsafeAtomicAdd(&o[2*c2 + 1], wv[j] * bf_hi(u[c2]));
                }
                unsafeAtomicAdd(&o[CCH], wv[j]);
            }
        }
    }
}

// Block per SOURCE bucket: stream records once, accumulate 9 target partials
// in registers, LDS-reduce, atomic-add into fsum, then semaphore-finalize
// any target whose contributions are now complete.
__global__ __launch_bounds__(STPB) void spx_scan_kernel(
    const unsigned* __restrict__ recF,    // [B*K][cap][16]
    const unsigned* __restrict__ recW,    // [B*K][cap][8]
    const int*      __restrict__ cnt,     // [B*K][CNTS]
    const int*      __restrict__ nw_p,
    const int*      __restrict__ nh_p,
    float*          __restrict__ fsum,    // [B*K][CCH+1]
    int*            __restrict__ done,    // [B*K] semaphores (pre-zeroed)
    float*          __restrict__ out,     // [B][C][K]
    int K, int cap)
{
    __shared__ float red[32][9][CCH + 1];   // 38 KB
    __shared__ int   win[9];
    __shared__ float F[CCH + 1];

    const int bs  = blockIdx.x;             // b*K + s
    const int tid = threadIdx.x;
    const int c2  = tid & 15;               // channel pair
    const int g   = tid >> 4;               // record group 0..31

    int c = cnt[bs * CNTS];
    if (c > cap) c = cap;
    const int b = bs / K;
    const unsigned* rF = recF + (size_t)bs * cap * 16;
    const unsigned* rW = recW + (size_t)bs * cap * 8;

    float a[9][2], ws9[9];
#pragma unroll
    for (int j = 0; j < 9; ++j) { a[j][0] = 0.f; a[j][1] = 0.f; ws9[j] = 0.f; }

    for (int i = g; i < c; i += 32) {
        const unsigned uf = rF[(size_t)i * 16 + c2];
        const float f0 = bf_lo(uf), f1 = bf_hi(uf);
        const unsigned* rw = rW + (size_t)i * 8;
        const unsigned wp0 = rw[0], wp1 = rw[1], wp2 = rw[2],
                       wp3 = rw[3], wp4 = rw[4];
        const float w[9] = { bf_lo(wp0), bf_hi(wp0), bf_lo(wp1), bf_hi(wp1),
                             bf_lo(wp2), bf_hi(wp2), bf_lo(wp3), bf_hi(wp3),
                             bf_lo(wp4) };
#pragma unroll
        for (int j = 0; j < 9; ++j) {
            a[j][0] += w[j] * f0;
            a[j][1] += w[j] * f1;
            ws9[j]  += w[j];
        }
    }

#pragma unroll
    for (int j = 0; j < 9; ++j) {
        red[g][j][2 * c2]     = a[j][0];
        red[g][j][2 * c2 + 1] = a[j][1];
    }
    if (c2 == 0) {
#pragma unroll
        for (int j = 0; j < 9; ++j) red[g][j][CCH] = ws9[j];
    }
    __syncthreads();

    const int s  = bs - b * K;
    const int nw = nw_p[0];
    const int nh = nh_p[0];
    const int sy = s / nw;
    const int sx = s - sy * nw;

    for (int col = tid; col < 9 * (CCH + 1); col += STPB) {
        const int j  = col / (CCH + 1);
        const int cc = col - j * (CCH + 1);
        const int ty = sy + j / 3 - 1;
        const int tx = sx + j % 3 - 1;
        if (tx < 0 || tx >= nw || ty < 0 || ty >= nh) continue;
        float sum = 0.f;
#pragma unroll
        for (int g2 = 0; g2 < 32; ++g2) sum += red[g2][j][cc];
        unsafeAtomicAdd(&fsum[(size_t)(b * K + ty * nw + tx) * (CCH + 1) + cc],
                        sum);
    }

    // barrier drains this block's fsum atomics (vmcnt(0) before s_barrier)
    __syncthreads();

    if (tid < 9) {
        const int j  = tid;
        const int ty = sy + j / 3 - 1;
        const int tx = sx + j % 3 - 1;
        int w = -1;
        if (tx >= 0 && tx < nw && ty >= 0 && ty < nh) {
            const int t    = b * K + ty * nw + tx;
            const int cnty = 3 - (ty == 0) - (ty == nh - 1);
            const int cntx = 3 - (tx == 0) - (tx == nw - 1);
            const int old  = __hip_atomic_fetch_add(
                &done[t], 1, __ATOMIC_ACQ_REL, __HIP_MEMORY_SCOPE_AGENT);
            if (old == cnty * cntx - 1) w = t;   // we complete this target
        }
        win[j] = w;
    }
    __syncthreads();

    for (int j = 0; j < 9; ++j) {
        const int t = win[j];
        if (t < 0) continue;
        if (tid < CCH + 1) {
            F[tid] = __hip_atomic_load(&fsum[(size_t)t * (CCH + 1) + tid],
                                       __ATOMIC_RELAXED,
                                       __HIP_MEMORY_SCOPE_AGENT);
        }
        __syncthreads();
        if (tid < CCH) {
            const float W  = F[CCH];
            const int   bb = t / K;
            const int   kk = t - bb * K;
            out[((size_t)bb * CCH + tid) * K + kk] =
                (W > 1e-16f) ? (F[tid] / W) : 0.f;
        }
        __syncthreads();
    }
}

extern "C" void kernel_launch(void* const* d_in, const int* in_sizes, int n_in,
                              void* d_out, int out_size, void* d_ws, size_t ws_size,
                              hipStream_t stream) {
    const float* pf     = (const float*)d_in[0];
    const float* assoc  = (const float*)d_in[1];
    const int*   idxmap = (const int*)d_in[2];
    const int*   nw_p   = (const int*)d_in[3];
    const int*   nh_p   = (const int*)d_in[4];
    float* out = (float*)d_out;

    const int BP = in_sizes[2];          // B*P = 262144
    const int B  = 4;                    // fixed by reference setup
    const int P  = BP / B;               // 65536
    const int K  = out_size / (B * CCH); // 256 (== KMAX)

    // ws: cnt [B*K][CNTS] | fsum [B*K][33] | done [B*K] |
    //     recF [B*K][cap][64B] | recW [B*K][cap][32B]
    const size_t cnt_bytes  = (size_t)B * K * CNTS * sizeof(int);
    const size_t fsum_bytes = (size_t)B * K * (CCH + 1) * sizeof(float);
    const size_t done_bytes = (size_t)B * K * sizeof(int);
    int*   cnt  = (int*)d_ws;
    float* fsum = (float*)((char*)d_ws + cnt_bytes);
    int*   done = (int*)((char*)d_ws + cnt_bytes + fsum_bytes);

    const size_t head = cnt_bytes + fsum_bytes + done_bytes;
    const size_t avail = (ws_size > head) ? (ws_size - head) : 0;
    int cap = (int)(avail / ((size_t)B * K * 24 * sizeof(unsigned)));
    if (cap > CAPC) cap = CAPC;
    if (cap < 1) cap = 1;

    unsigned* recF = (unsigned*)((char*)d_ws + head);
    unsigned* recW = recF + (size_t)B * K * cap * 16;

    hipMemsetAsync(cnt, 0, head, stream);   // cnt + fsum + done = 0

    const int bpb = P / TPB;             // 64 blocks per batch
    spx_prep_kernel<<<B * bpb, TPB, 0, stream>>>(
        pf, assoc, idxmap, nw_p, nh_p, cnt, recF, recW, fsum, P, K, cap, bpb);

    spx_scan_kernel<<<B * K, STPB, 0, stream>>>(
        recF, recW, cnt, nw_p, nh_p, fsum, done, out, K, cap);
}

// Round 18
// 109.377 us; speedup vs baseline: 1.2082x; 1.2082x over previous
//
#include <hip/hip_runtime.h>
#include <hip/hip_bf16.h>

// CalcSpixelFeats R18. Base = R14 (verified best, 109.9us). R15/R17 showed
// device-scope sync machinery in hot kernels costs more than the dispatch it
// replaces; R16 showed pixel-ordered records cost more than they save.
// R18 = R14 with ONE change: prep TPB 1024->512 (1 px/thread, 512 blocks).
// At 88 VGPR a 512-thr block is 8 waves = 2/SIMD -> 2 blocks/CU co-resident,
// so barrier drains + reservation-atomic latency overlap with the other
// block's streaming. Reservation atomics 65K->131K but over 1024 padded
// lines (the R5-7 wall was 262K on 16 lines).

#define CCH  32         // channels, fixed by problem
#define TPB  512        // prep block threads (1 px/thread) — 2 blocks/CU
#define STPB 512        // scan block: 16 ch-pair lanes x 32 record groups
#define CAPC 384        // bucket capacity (mean 256, sd 16 -> +8 sigma)
#define RECW 24         // record width in dwords (96 B)
#define CNTS 16         // counter stride in dwords (64 B line)
#define KMAX 256

__device__ __forceinline__ unsigned pack_bf16(float a, float b) {
    unsigned ua = __float_as_uint(a);
    unsigned ub = __float_as_uint(b);
    ua = (ua + 0x7FFFu + ((ua >> 16) & 1u)) >> 16;   // RNE
    ub = (ub + 0x7FFFu + ((ub >> 16) & 1u)) >> 16;
    return ua | (ub << 16);
}
__device__ __forceinline__ float bf_lo(unsigned u) {
    return __uint_as_float(u << 16);
}
__device__ __forceinline__ float bf_hi(unsigned u) {
    return __uint_as_float(u & 0xFFFF0000u);
}

__global__ __launch_bounds__(TPB, 4) void spx_prep_kernel(
    const float* __restrict__ pf,      // [B][C][P]
    const float* __restrict__ assoc,   // [B][9][P]
    const int*   __restrict__ idxmap,  // [B][P]
    const int*   __restrict__ nw_p,
    const int*   __restrict__ nh_p,
    int*         __restrict__ cnt,     // [B*K][CNTS] (padded counters)
    unsigned*    __restrict__ recs,    // [B*K][cap][RECW]
    float*       __restrict__ fsum,    // [B*K][CCH+1] target accumulator
    int P, int K, int cap, int bpb)    // bpb = P / TPB
{
    __shared__ int hist[KMAX];
    __shared__ int bases[KMAX];

    const int b   = blockIdx.x / bpb;
    const int blk = blockIdx.x - b * bpb;
    const int tid = threadIdx.x;
    const int p   = blk * TPB + tid;   // within batch (1 px/thread)

    if (tid < KMAX) hist[tid] = 0;
    __syncthreads();

    const int*   ix_b = idxmap + (size_t)b * P;
    const float* pf_b = pf     + (size_t)b * CCH * P;
    const float* as_b = assoc  + (size_t)b * 9 * P;

    const int idx  = ix_b[p];
    const int rank = atomicAdd(&hist[idx], 1);   // native LDS int atomic

    // bulk loads: all issue before the reservation barrier
    unsigned u[16];
#pragma unroll
    for (int c2 = 0; c2 < 16; ++c2) {
        const float f0 = pf_b[(size_t)(2*c2  ) * P + p];
        const float f1 = pf_b[(size_t)(2*c2+1) * P + p];
        u[c2] = pack_bf16(f0, f1);
    }
    float wv[9];
#pragma unroll
    for (int j = 0; j < 9; ++j) wv[j] = as_b[(size_t)j * P + p];

    __syncthreads();
    if (tid < KMAX)
        bases[tid] = atomicAdd(&cnt[(b * K + tid) * CNTS], hist[tid]);
    __syncthreads();

    const int pos = bases[idx] + rank;

    if (pos < cap) {
        unsigned* dst = recs + ((size_t)(b * K + idx) * cap + pos) * RECW;
        uint4* d4 = (uint4*)dst;
        d4[0] = make_uint4(u[0],  u[1],  u[2],  u[3]);
        d4[1] = make_uint4(u[4],  u[5],  u[6],  u[7]);
        d4[2] = make_uint4(u[8],  u[9],  u[10], u[11]);
        d4[3] = make_uint4(u[12], u[13], u[14], u[15]);
        d4[4] = make_uint4(pack_bf16(wv[0], wv[1]), pack_bf16(wv[2], wv[3]),
                           pack_bf16(wv[4], wv[5]), pack_bf16(wv[6], wv[7]));
        dst[20] = pack_bf16(wv[8], 0.0f);
    } else {
        // rare overflow: accumulate into fsum directly (native fp atomics)
        const int nw = nw_p[0], nh = nh_p[0];
        const int iy = idx / nw, ixx = idx - (idx / nw) * nw;
#pragma unroll
        for (int j = 0; j < 9; ++j) {
            const int ty = iy + j / 3 - 1, tx = ixx + j % 3 - 1;
            if (tx >= 0 && tx < nw && ty >= 0 && ty < nh) {
                float* o = fsum + (size_t)(b * K + ty * nw + tx) * (CCH + 1);
#pragma unroll
                for (int c2 = 0; c2 < 16; ++c2) {
                    unsafeAtomicAdd(&o[2*c2],     wv[j] * bf_lo(u[c2]));
                    unsafeAtomicAdd(&o[2*c2 + 1], wv[j] * bf_hi(u[c2]));
                }
                unsafeAtomicAdd(&o[CCH], wv[j]);
            }
        }
    }
}

// Block per SOURCE bucket: stream records once, accumulate 9 target partials
// (features + per-j wsum) in registers, LDS-reduce, atomically add the 9
// reduced [33]-vectors into their target bins in fsum.
__global__ __launch_bounds__(STPB) void spx_scan_kernel(
    const unsigned* __restrict__ recs,    // [B*K][cap][RECW]
    const int*      __restrict__ cnt,     // [B*K][CNTS]
    const int*      __restrict__ nw_p,
    const int*      __restrict__ nh_p,
    float*          __restrict__ fsum,    // [B*K][CCH+1]
    int K, int cap)
{
    __shared__ float red[32][9][CCH + 1];   // 38 KB

    const int bs  = blockIdx.x;             // b*K + s
    const int tid = threadIdx.x;
    const int c2  = tid & 15;               // channel pair
    const int g   = tid >> 4;               // record group 0..31

    int c = cnt[bs * CNTS];
    if (c > cap) c = cap;
    const unsigned* rb = recs + (size_t)bs * cap * RECW;

    float a[9][2], ws9[9];
#pragma unroll
    for (int j = 0; j < 9; ++j) { a[j][0] = 0.f; a[j][1] = 0.f; ws9[j] = 0.f; }

    for (int i = g; i < c; i += 32) {
        const unsigned* r = rb + (size_t)i * RECW;
        const unsigned uf  = r[c2];
        const float f0 = bf_lo(uf), f1 = bf_hi(uf);
        const unsigned wp0 = r[16], wp1 = r[17], wp2 = r[18],
                       wp3 = r[19], wp4 = r[20];
        const float w[9] = { bf_lo(wp0), bf_hi(wp0), bf_lo(wp1), bf_hi(wp1),
                             bf_lo(wp2), bf_hi(wp2), bf_lo(wp3), bf_hi(wp3),
                             bf_lo(wp4) };
#pragma unroll
        for (int j = 0; j < 9; ++j) {
            a[j][0] += w[j] * f0;
            a[j][1] += w[j] * f1;
            ws9[j]  += w[j];
        }
    }

#pragma unroll
    for (int j = 0; j < 9; ++j) {
        red[g][j][2 * c2]     = a[j][0];
        red[g][j][2 * c2 + 1] = a[j][1];
    }
    if (c2 == 0) {
#pragma unroll
        for (int j = 0; j < 9; ++j) red[g][j][CCH] = ws9[j];
    }
    __syncthreads();

    const int b  = bs / K;
    const int s  = bs - b * K;
    const int nw = nw_p[0];
    const int nh = nh_p[0];
    const int sy = s / nw;
    const int sx = s - sy * nw;

    for (int col = tid; col < 9 * (CCH + 1); col += STPB) {
        const int j  = col / (CCH + 1);
        const int cc = col - j * (CCH + 1);
        const int ty = sy + j / 3 - 1;
        const int tx = sx + j % 3 - 1;
        if (tx < 0 || tx >= nw || ty < 0 || ty >= nh) continue;
        float sum = 0.f;
#pragma unroll
        for (int g2 = 0; g2 < 32; ++g2) sum += red[g2][j][cc];
        unsafeAtomicAdd(&fsum[(size_t)(b * K + ty * nw + tx) * (CCH + 1) + cc],
                        sum);
    }
}

// Trivial finalize: one thread per output element (b,c,k), k fastest ->
// coalesced writes; fsum reads hit L2 (135 KB).
__global__ __launch_bounds__(256) void spx_finalize_kernel(
    const float* __restrict__ fsum,  // [B*K][CCH+1]
    float*       __restrict__ out,   // [B][C][K]
    int K, int total)
{
    const int gid = blockIdx.x * 256 + threadIdx.x;
    if (gid >= total) return;
    const int k = gid % K;
    const int c = (gid / K) % CCH;
    const int b = gid / (K * CCH);
    const float* f = fsum + (size_t)(b * K + k) * (CCH + 1);
    const float W = f[CCH];
    out[gid] = (W > 1e-16f) ? (f[c] / W) : 0.f;
}

extern "C" void kernel_launch(void* const* d_in, const int* in_sizes, int n_in,
                              void* d_out, int out_size, void* d_ws, size_t ws_size,
                              hipStream_t stream) {
    const float* pf     = (const float*)d_in[0];
    const float* assoc  = (const float*)d_in[1];
    const int*   idxmap = (const int*)d_in[2];
    const int*   nw_p   = (const int*)d_in[3];
    const int*   nh_p   = (const int*)d_in[4];
    float* out = (float*)d_out;

    const int BP = in_sizes[2];          // B*P = 262144
    const int B  = 4;                    // fixed by reference setup
    const int P  = BP / B;               // 65536
    const int K  = out_size / (B * CCH); // 256 (== KMAX)

    // ws: cnt [B*K][CNTS] | fsum [B*K][33] | recs [B*K][cap][96B]
    const size_t cnt_bytes  = (size_t)B * K * CNTS * sizeof(int);
    const size_t fsum_bytes = (size_t)B * K * (CCH + 1) * sizeof(float);
    int*      cnt  = (int*)d_ws;
    float*    fsum = (float*)((char*)d_ws + cnt_bytes);
    unsigned* recs = (unsigned*)((char*)d_ws + cnt_bytes + fsum_bytes);

    const size_t used  = cnt_bytes + fsum_bytes;
    const size_t avail = (ws_size > used) ? (ws_size - used) : 0;
    int cap = (int)(avail / ((size_t)B * K * RECW * sizeof(unsigned)));
    if (cap > CAPC) cap = CAPC;
    if (cap < 1) cap = 1;

    hipMemsetAsync(cnt, 0, cnt_bytes + fsum_bytes, stream);  // cnt+fsum = 0

    const int bpb = P / TPB;             // 128 blocks per batch
    spx_prep_kernel<<<B * bpb, TPB, 0, stream>>>(
        pf, assoc, idxmap, nw_p, nh_p, cnt, recs, fsum, P, K, cap, bpb);

    spx_scan_kernel<<<B * K, STPB, 0, stream>>>(
        recs, cnt, nw_p, nh_p, fsum, K, cap);

    const int total = B * K * CCH;
    spx_finalize_kernel<<<(total + 255) / 256, 256, 0, stream>>>(
        fsum, out, K, total);
}

// Round 19
// 107.564 us; speedup vs baseline: 1.2285x; 1.0169x over previous
//
#include <hip/hip_runtime.h>
#include <hip/hip_bf16.h>

// CalcSpixelFeats R19. Base = R18 (109.4us best). Plateau mapping complete:
// R15/R16/R17 structural levers all negative; R18 residency x2 neutral.
// R19 is a low-risk micro-pass on scan: the inner loop issued 6 load
// instructions per record (1 feat + 5 scalar w dwords); record base is
// 96B-aligned so r+16 is 16B-aligned -> wp0..3 as ONE uint4 load (6->3).
// Everything else identical to R18.

#define CCH  32         // channels, fixed by problem
#define TPB  512        // prep block threads (1 px/thread) — 2 blocks/CU
#define STPB 512        // scan block: 16 ch-pair lanes x 32 record groups
#define CAPC 384        // bucket capacity (mean 256, sd 16 -> +8 sigma)
#define RECW 24         // record width in dwords (96 B)
#define CNTS 16         // counter stride in dwords (64 B line)
#define KMAX 256

__device__ __forceinline__ unsigned pack_bf16(float a, float b) {
    unsigned ua = __float_as_uint(a);
    unsigned ub = __float_as_uint(b);
    ua = (ua + 0x7FFFu + ((ua >> 16) & 1u)) >> 16;   // RNE
    ub = (ub + 0x7FFFu + ((ub >> 16) & 1u)) >> 16;
    return ua | (ub << 16);
}
__device__ __forceinline__ float bf_lo(unsigned u) {
    return __uint_as_float(u << 16);
}
__device__ __forceinline__ float bf_hi(unsigned u) {
    return __uint_as_float(u & 0xFFFF0000u);
}

__global__ __launch_bounds__(TPB, 4) void spx_prep_kernel(
    const float* __restrict__ pf,      // [B][C][P]
    const float* __restrict__ assoc,   // [B][9][P]
    const int*   __restrict__ idxmap,  // [B][P]
    const int*   __restrict__ nw_p,
    const int*   __restrict__ nh_p,
    int*         __restrict__ cnt,     // [B*K][CNTS] (padded counters)
    unsigned*    __restrict__ recs,    // [B*K][cap][RECW]
    float*       __restrict__ fsum,    // [B*K][CCH+1] target accumulator
    int P, int K, int cap, int bpb)    // bpb = P / TPB
{
    __shared__ int hist[KMAX];
    __shared__ int bases[KMAX];

    const int b   = blockIdx.x / bpb;
    const int blk = blockIdx.x - b * bpb;
    const int tid = threadIdx.x;
    const int p   = blk * TPB + tid;   // within batch (1 px/thread)

    if (tid < KMAX) hist[tid] = 0;
    __syncthreads();

    const int*   ix_b = idxmap + (size_t)b * P;
    const float* pf_b = pf     + (size_t)b * CCH * P;
    const float* as_b = assoc  + (size_t)b * 9 * P;

    const int idx  = ix_b[p];
    const int rank = atomicAdd(&hist[idx], 1);   // native LDS int atomic

    // bulk loads: all issue before the reservation barrier
    unsigned u[16];
#pragma unroll
    for (int c2 = 0; c2 < 16; ++c2) {
        const float f0 = pf_b[(size_t)(2*c2  ) * P + p];
        const float f1 = pf_b[(size_t)(2*c2+1) * P + p];
        u[c2] = pack_bf16(f0, f1);
    }
    float wv[9];
#pragma unroll
    for (int j = 0; j < 9; ++j) wv[j] = as_b[(size_t)j * P + p];

    __syncthreads();
    if (tid < KMAX)
        bases[tid] = atomicAdd(&cnt[(b * K + tid) * CNTS], hist[tid]);
    __syncthreads();

    const int pos = bases[idx] + rank;

    if (pos < cap) {
        unsigned* dst = recs + ((size_t)(b * K + idx) * cap + pos) * RECW;
        uint4* d4 = (uint4*)dst;
        d4[0] = make_uint4(u[0],  u[1],  u[2],  u[3]);
        d4[1] = make_uint4(u[4],  u[5],  u[6],  u[7]);
        d4[2] = make_uint4(u[8],  u[9],  u[10], u[11]);
        d4[3] = make_uint4(u[12], u[13], u[14], u[15]);
        d4[4] = make_uint4(pack_bf16(wv[0], wv[1]), pack_bf16(wv[2], wv[3]),
                           pack_bf16(wv[4], wv[5]), pack_bf16(wv[6], wv[7]));
        dst[20] = pack_bf16(wv[8], 0.0f);
    } else {
        // rare overflow: accumulate into fsum directly (native fp atomics)
        const int nw = nw_p[0], nh = nh_p[0];
        const int iy = idx / nw, ixx = idx - (idx / nw) * nw;
#pragma unroll
        for (int j = 0; j < 9; ++j) {
            const int ty = iy + j / 3 - 1, tx = ixx + j % 3 - 1;
            if (tx >= 0 && tx < nw && ty >= 0 && ty < nh) {
                float* o = fsum + (size_t)(b * K + ty * nw + tx) * (CCH + 1);
#pragma unroll
                for (int c2 = 0; c2 < 16; ++c2) {
                    unsafeAtomicAdd(&o[2*c2],     wv[j] * bf_lo(u[c2]));
                    unsafeAtomicAdd(&o[2*c2 + 1], wv[j] * bf_hi(u[c2]));
                }
                unsafeAtomicAdd(&o[CCH], wv[j]);
            }
        }
    }
}

// Block per SOURCE bucket: stream records once, accumulate 9 target partials
// (features + per-j wsum) in registers, LDS-reduce, atomically add the 9
// reduced [33]-vectors into their target bins in fsum.
__global__ __launch_bounds__(STPB, 4) void spx_scan_kernel(
    const unsigned* __restrict__ recs,    // [B*K][cap][RECW]
    const int*      __restrict__ cnt,     // [B*K][CNTS]
    const int*      __restrict__ nw_p,
    const int*      __restrict__ nh_p,
    float*          __restrict__ fsum,    // [B*K][CCH+1]
    int K, int cap)
{
    __shared__ float red[32][9][CCH + 1];   // 38 KB

    const int bs  = blockIdx.x;             // b*K + s
    const int tid = threadIdx.x;
    const int c2  = tid & 15;               // channel pair
    const int g   = tid >> 4;               // record group 0..31

    int c = cnt[bs * CNTS];
    if (c > cap) c = cap;
    const unsigned* rb = recs + (size_t)bs * cap * RECW;

    float a[9][2], ws9[9];
#pragma unroll
    for (int j = 0; j < 9; ++j) { a[j][0] = 0.f; a[j][1] = 0.f; ws9[j] = 0.f; }

    for (int i = g; i < c; i += 32) {
        const unsigned* r = rb + (size_t)i * RECW;
        const unsigned uf = r[c2];
        const float f0 = bf_lo(uf), f1 = bf_hi(uf);
        // r is 96B-aligned -> r+16 is 16B-aligned: one uint4 + one dword
        const uint4    wq = *(const uint4*)(r + 16);
        const unsigned w8 = r[20];
        const float w[9] = { bf_lo(wq.x), bf_hi(wq.x), bf_lo(wq.y),
                             bf_hi(wq.y), bf_lo(wq.z), bf_hi(wq.z),
                             bf_lo(wq.w), bf_hi(wq.w), bf_lo(w8) };
#pragma unroll
        for (int j = 0; j < 9; ++j) {
            a[j][0] += w[j] * f0;
            a[j][1] += w[j] * f1;
            ws9[j]  += w[j];
        }
    }

#pragma unroll
    for (int j = 0; j < 9; ++j) {
        red[g][j][2 * c2]     = a[j][0];
        red[g][j][2 * c2 + 1] = a[j][1];
    }
    if (c2 == 0) {
#pragma unroll
        for (int j = 0; j < 9; ++j) red[g][j][CCH] = ws9[j];
    }
    __syncthreads();

    const int b  = bs / K;
    const int s  = bs - b * K;
    const int nw = nw_p[0];
    const int nh = nh_p[0];
    const int sy = s / nw;
    const int sx = s - sy * nw;

    for (int col = tid; col < 9 * (CCH + 1); col += STPB) {
        const int j  = col / (CCH + 1);
        const int cc = col - j * (CCH + 1);
        const int ty = sy + j / 3 - 1;
        const int tx = sx + j % 3 - 1;
        if (tx < 0 || tx >= nw || ty < 0 || ty >= nh) continue;
        float sum = 0.f;
#pragma unroll
        for (int g2 = 0; g2 < 32; ++g2) sum += red[g2][j][cc];
        unsafeAtomicAdd(&fsum[(size_t)(b * K + ty * nw + tx) * (CCH + 1) + cc],
                        sum);
    }
}

// Trivial finalize: one thread per output element (b,c,k), k fastest ->
// coalesced writes; fsum reads hit L2 (135 KB).
__global__ __launch_bounds__(256) void spx_finalize_kernel(
    const float* __restrict__ fsum,  // [B*K][CCH+1]
    float*       __restrict__ out,   // [B][C][K]
    int K, int total)
{
    const int gid = blockIdx.x * 256 + threadIdx.x;
    if (gid >= total) return;
    const int k = gid % K;
    const int c = (gid / K) % CCH;
    const int b = gid / (K * CCH);
    const float* f = fsum + (size_t)(b * K + k) * (CCH + 1);
    const float W = f[CCH];
    out[gid] = (W > 1e-16f) ? (f[c] / W) : 0.f;
}

extern "C" void kernel_launch(void* const* d_in, const int* in_sizes, int n_in,
                              void* d_out, int out_size, void* d_ws, size_t ws_size,
                              hipStream_t stream) {
    const float* pf     = (const float*)d_in[0];
    const float* assoc  = (const float*)d_in[1];
    const int*   idxmap = (const int*)d_in[2];
    const int*   nw_p   = (const int*)d_in[3];
    const int*   nh_p   = (const int*)d_in[4];
    float* out = (float*)d_out;

    const int BP = in_sizes[2];          // B*P = 262144
    const int B  = 4;                    // fixed by reference setup
    const int P  = BP / B;               // 65536
    const int K  = out_size / (B * CCH); // 256 (== KMAX)

    // ws: cnt [B*K][CNTS] | fsum [B*K][33] | recs [B*K][cap][96B]
    const size_t cnt_bytes  = (size_t)B * K * CNTS * sizeof(int);
    const size_t fsum_bytes = (size_t)B * K * (CCH + 1) * sizeof(float);
    int*      cnt  = (int*)d_ws;
    float*    fsum = (float*)((char*)d_ws + cnt_bytes);
    unsigned* recs = (unsigned*)((char*)d_ws + cnt_bytes + fsum_bytes);

    const size_t used  = cnt_bytes + fsum_bytes;
    const size_t avail = (ws_size > used) ? (ws_size - used) : 0;
    int cap = (int)(avail / ((size_t)B * K * RECW * sizeof(unsigned)));
    if (cap > CAPC) cap = CAPC;
    if (cap < 1) cap = 1;

    hipMemsetAsync(cnt, 0, cnt_bytes + fsum_bytes, stream);  // cnt+fsum = 0

    const int bpb = P / TPB;             // 128 blocks per batch
    spx_prep_kernel<<<B * bpb, TPB, 0, stream>>>(
        pf, assoc, idxmap, nw_p, nh_p, cnt, recs, fsum, P, K, cap, bpb);

    spx_scan_kernel<<<B * K, STPB, 0, stream>>>(
        recs, cnt, nw_p, nh_p, fsum, K, cap);

    const int total = B * K * CCH;
    spx_finalize_kernel<<<(total + 255) / 256, 256, 0, stream>>>(
        fsum, out, K, total);
}